// Round 14
// baseline (129.669 us; speedup 1.0000x reference)
//
#include <hip/hip_runtime.h>
#include <math.h>

// CapsuleLinear dynamic routing, `priors` never materialized.
//   s[b,o,i]   = sum_n prob[b,o,n] * x[b,n,i]
//   out[b,o,l] = sum_i W[o,l,i] * s[b,o,i]
//   logits[b,o,n] = x[b,n,:] . T[b,o,:],  T accumulates t_r[o,i] = sum_l W[o,l,i]*v_r[o,l]
//
// R14: R13 (120.6us best) minus one kernel boundary. R6's init+pass fusion
// failed because its redundant init re-read L3-cold x once per XCD (8 L2s,
// FETCH 20.5 MB). R13 proved the d%8->XCD round-robin mapping is real
// (aligning k_init/kC on it gained 10us). With DECODE_BC, all 16 blocks of
// batch b sit on XCD b/4 -> a redundant init reads the slab from its own L2
// after one HBM miss per batch. So: kA = fused init+pass1 (R6 structure +
// R13 decode + stride-33 t_lds), c==0 publishes T0 for kB. kB/kC identical
// to R13. Chain: kA -> kB -> kC (3 kernels, 2 boundaries).
// Failure signature (mapping false): kA >= 40us, FETCH ~20 MB -> revert R13.

#define N_B      32
#define IN_CAPS  1152
#define IN_LEN   32
#define OUT_CAPS 64
#define OUT_LEN  32

#define NCHUNK 16                    // n-chunks per batch -> 512 pass blocks
#define NPB    (IN_CAPS / NCHUNK)    // 72 n per block
#define PASS_WAVES 4                 // 256-thread pass blocks
#define NPW    (NPB / PASS_WAVES)    // 18 n per wave
#define TSTR   33                    // t_lds row stride: bank (o+i)%32, conflict-free
#define FSTR   36                    // flush buf row stride (16B-aligned, R7-proven)

// XCD-aware decode of blockIdx.x -> (b,c): presumed round-robin XCD = d&7;
// each XCD gets 4 whole batches. Bijective (512%8==0). R13-validated.
#define DECODE_BC(d, b, c) \
    const int _slot = (d) >> 3; \
    const int b = ((d) & 7) * 4 + (_slot >> 4); \
    const int c = _slot & 15;

// DPP helper: butterfly step, all lanes valid.
#define DPPV(v, ctrl) \
    __int_as_float(__builtin_amdgcn_update_dpp(0, __float_as_int(v), ctrl, 0xF, 0xF, true))

__device__ __forceinline__ float wave_max(float v) {
    v = fmaxf(v, DPPV(v, 0xB1));         // quad_perm xor1
    v = fmaxf(v, DPPV(v, 0x4E));         // quad_perm xor2
    v = fmaxf(v, DPPV(v, 0x141));        // row_half_mirror
    v = fmaxf(v, DPPV(v, 0x140));        // row_mirror
    v = fmaxf(v, __shfl_xor(v, 16, 64)); // cross-row (proven path)
    v = fmaxf(v, __shfl_xor(v, 32, 64));
    return v;
}
__device__ __forceinline__ float wave_sum(float v) {
    v += DPPV(v, 0xB1);
    v += DPPV(v, 0x4E);
    v += DPPV(v, 0x141);
    v += DPPV(v, 0x140);
    v += __shfl_xor(v, 16, 64);
    v += __shfl_xor(v, 32, 64);
    return v;
}

// ---------------------------------------------------------------------------
// Pass body (R12/R13-proven): logits read t from conflict-free stride-33
// LDS, x rows via broadcast VMEM, DPP+shfl softmax (lane = o), s[32] in
// regs. Flush: padded-LDS block reduce -> part[b,c] slab.
// ---------------------------------------------------------------------------
__device__ __forceinline__ void pass_v2(const float* __restrict__ x,
                                        const float* t_lds,   // [64*TSTR], filled
                                        float* buf,           // [4*64*FSTR]
                                        float* __restrict__ part_out,
                                        int b, int c, int tid, int lane, int wave) {
    float s[IN_LEN];
#pragma unroll
    for (int i = 0; i < IN_LEN; ++i) s[i] = 0.f;

    const float* xw = x + ((size_t)b * IN_CAPS + c * NPB + wave * NPW) * IN_LEN;
    const float* tr = t_lds + lane * TSTR;

#define L4(acc, R, k) \
    acc = fmaf((R).x, tr[k],     acc); acc = fmaf((R).y, tr[k + 1], acc); \
    acc = fmaf((R).z, tr[k + 2], acc); acc = fmaf((R).w, tr[k + 3], acc);
#define S4(R, k) \
    s[k]     = fmaf(prob, (R).x, s[k]);     s[k + 1] = fmaf(prob, (R).y, s[k + 1]); \
    s[k + 2] = fmaf(prob, (R).z, s[k + 2]); s[k + 3] = fmaf(prob, (R).w, s[k + 3]);

#pragma unroll
    for (int j = 0; j < NPW; ++j) {
        const float4* xr = (const float4*)(xw + j * IN_LEN);  // wave-uniform addr
        const float4 r0 = xr[0], r1 = xr[1], r2 = xr[2], r3 = xr[3],
                     r4 = xr[4], r5 = xr[5], r6 = xr[6], r7 = xr[7];

        float l0 = 0.f, l1 = 0.f, l2 = 0.f, l3 = 0.f;
        L4(l0, r0, 0)  L4(l1, r1, 4)  L4(l2, r2, 8)  L4(l3, r3, 12)
        L4(l0, r4, 16) L4(l1, r5, 20) L4(l2, r6, 24) L4(l3, r7, 28)
        const float logit = (l0 + l1) + (l2 + l3);

        const float m = wave_max(logit);
        const float p = __expf(logit - m);
        const float S = wave_sum(p);
        const float prob = p * __builtin_amdgcn_rcpf(S);

        S4(r0, 0)  S4(r1, 4)  S4(r2, 8)  S4(r3, 12)
        S4(r4, 16) S4(r5, 20) S4(r6, 24) S4(r7, 28)
    }
#undef L4
#undef S4

    // flush: per-wave rows into padded buf, block-reduce, write part[b,c]
    {
        float4* dst = (float4*)&buf[(wave * OUT_CAPS + lane) * FSTR];
#pragma unroll
        for (int q = 0; q < 8; ++q)
            dst[q] = make_float4(s[4 * q], s[4 * q + 1], s[4 * q + 2], s[4 * q + 3]);
    }
    __syncthreads();
    {
        float4* pb4 = (float4*)(part_out + ((size_t)b * NCHUNK + c) * OUT_CAPS * IN_LEN);
        for (int e = tid; e < OUT_CAPS * IN_LEN / 4; e += 256) {
            const int o = e >> 3, q4 = (e & 7) * 4;
            const float4 a0 = *(const float4*)&buf[(0 * OUT_CAPS + o) * FSTR + q4];
            const float4 a1 = *(const float4*)&buf[(1 * OUT_CAPS + o) * FSTR + q4];
            const float4 a2 = *(const float4*)&buf[(2 * OUT_CAPS + o) * FSTR + q4];
            const float4 a3 = *(const float4*)&buf[(3 * OUT_CAPS + o) * FSTR + q4];
            pb4[e] = make_float4(a0.x + a1.x + a2.x + a3.x,
                                 a0.y + a1.y + a2.y + a3.y,
                                 a0.z + a1.z + a2.z + a3.z,
                                 a0.w + a1.w + a2.w + a3.w);
        }
    }
}

// ---------------------------------------------------------------------------
// kA: fused init + pass1. Redundant init per block (XCD-local: all 16 blocks
// of batch b on XCD b/4, slab hits own L2 after one HBM miss). T0 -> stride-
// 33 t_lds; c==0 publishes T0 to global for kB. Then pass_v2 -> part.
// ---------------------------------------------------------------------------
__global__ __launch_bounds__(256, 2) void kA(const float* __restrict__ x,
                                             const float* __restrict__ W,
                                             float* __restrict__ T,
                                             float* __restrict__ part) {
    DECODE_BC(blockIdx.x, b, c)
    const int tid  = threadIdx.x;
    const int lane = tid & 63;
    const int wave = __builtin_amdgcn_readfirstlane(tid >> 6);

    __shared__ float t_lds[OUT_CAPS * TSTR];                          // 8.25 KB
    __shared__ __align__(16) float buf[PASS_WAVES * OUT_CAPS * FSTR]; // 36 KB

    const float* xb = x + (size_t)b * IN_CAPS * IN_LEN;

    // ---- init phase (R6-proven structure, now XCD-local) ----
    {
        float4* red4 = (float4*)buf;                   // [32][8] float4 = 4 KB
        const int q = tid & 7, g = tid >> 3;
        float4 acc = make_float4(0.f, 0.f, 0.f, 0.f);
        for (int n = g; n < IN_CAPS; n += 32) {
            const float4 v = *(const float4*)(xb + n * IN_LEN + q * 4);
            acc.x += v.x; acc.y += v.y; acc.z += v.z; acc.w += v.w;
        }
        red4[g * 8 + q] = acc;
    }
    __syncthreads();
    float* u     = buf + 1024;   // 2048 floats
    float* scale = buf + 3072;   // 64
    float* s0    = buf + 3136;   // 32
    if (tid < 8) {
        const float4* red4 = (const float4*)buf;
        float4 v = make_float4(0.f, 0.f, 0.f, 0.f);
        for (int g = 0; g < 32; ++g) {
            const float4 r = red4[g * 8 + tid];
            v.x += r.x; v.y += r.y; v.z += r.z; v.w += r.w;
        }
        const float inv = 1.f / 64.f;       // uniform softmax prob at r=0
        s0[tid * 4 + 0] = v.x * inv;
        s0[tid * 4 + 1] = v.y * inv;
        s0[tid * 4 + 2] = v.z * inv;
        s0[tid * 4 + 3] = v.w * inv;
    }
    __syncthreads();

    for (int e = tid; e < OUT_CAPS * OUT_LEN; e += 256) {
        const float* wrow = W + (size_t)e * IN_LEN;
        float a = 0.f;
#pragma unroll
        for (int i = 0; i < IN_LEN; ++i) a = fmaf(wrow[i], s0[i], a);
        u[e] = a;
    }
    __syncthreads();
    if (tid < OUT_CAPS) {
        float ns = 0.f;
#pragma unroll
        for (int l = 0; l < OUT_LEN; ++l) { const float v = u[tid * OUT_LEN + l]; ns = fmaf(v, v, ns); }
        scale[tid] = sqrtf(ns) / (1.f + ns);
    }
    __syncthreads();

    // T0 -> t_lds (stride 33); c==0 also publishes to global for kB
    for (int e = tid; e < OUT_CAPS * IN_LEN; e += 256) {
        const int o = e >> 5, i = e & 31;
        float a = 0.f;
#pragma unroll
        for (int l = 0; l < OUT_LEN; ++l)
            a = fmaf(W[((size_t)o * OUT_LEN + l) * IN_LEN + i], u[o * OUT_LEN + l], a);
        const float val = a * scale[o];
        t_lds[o * TSTR + i] = val;
        if (c == 0) T[(size_t)b * OUT_CAPS * IN_LEN + e] = val;
    }
    __syncthreads();        // also fences buf reads (u/scale) before pass reuses it

    pass_v2(x, t_lds, buf, part, b, c, tid, lane, wave);
}

// ---------------------------------------------------------------------------
// kB: redundant vt-reduce, wave-split (R13-proven); s -> u -> squash;
//     T1 = T0 + W^T v1 into stride-33 LDS; then routing iter 2 -> part2.
// ---------------------------------------------------------------------------
__global__ __launch_bounds__(256, 2) void kB(const float* __restrict__ x,
                                             const float* __restrict__ W,
                                             const float* __restrict__ T,
                                             const float* __restrict__ part,
                                             float* __restrict__ part2) {
    DECODE_BC(blockIdx.x, b, c)
    const int tid  = threadIdx.x;
    const int lane = tid & 63;
    const int wave = __builtin_amdgcn_readfirstlane(tid >> 6);

    __shared__ float t_lds[OUT_CAPS * TSTR];                          // 8.25 KB
    __shared__ __align__(16) float buf[PASS_WAVES * OUT_CAPS * FSTR]; // 36 KB

    float* uu = buf + 2048;   // 2048 floats
    float* sc = buf + 4096;   // 64

    // ---- vt-reduce, wave-split: 4x memory parallelism, chain depth 8x4 ----
    {
        const float4* pb4 = (const float4*)(part + (size_t)b * NCHUNK * OUT_CAPS * IN_LEN);
        float4* wp = (float4*)buf + wave * 512;
        for (int e = lane; e < 512; e += 64) {
            float4 acc = make_float4(0.f, 0.f, 0.f, 0.f);
#pragma unroll
            for (int k = 0; k < 4; ++k) {
                const float4 v = pb4[(size_t)(wave + 4 * k) * 512 + e];
                acc.x += v.x; acc.y += v.y; acc.z += v.z; acc.w += v.w;
            }
            wp[e] = acc;
        }
    }
    __syncthreads();
    {
        float4* b4 = (float4*)buf;
        for (int e = tid; e < 512; e += 256) {
            const float4 a0 = b4[e], a1 = b4[512 + e], a2 = b4[1024 + e], a3 = b4[1536 + e];
            b4[e] = make_float4(a0.x + a1.x + a2.x + a3.x,
                                a0.y + a1.y + a2.y + a3.y,
                                a0.z + a1.z + a2.z + a3.z,
                                a0.w + a1.w + a2.w + a3.w);   // s -> buf[0..2048)
        }
    }
    __syncthreads();

    for (int e = tid; e < OUT_CAPS * OUT_LEN; e += 256) {
        const int o = e >> 5;
        const float* wrow = W + (size_t)e * IN_LEN;
        const float* srow = buf + o * IN_LEN;
        float a = 0.f;
#pragma unroll
        for (int i = 0; i < IN_LEN; ++i) a = fmaf(wrow[i], srow[i], a);
        uu[e] = a;
    }
    __syncthreads();
    if (tid < OUT_CAPS) {
        float ns = 0.f;
#pragma unroll
        for (int l = 0; l < OUT_LEN; ++l) { const float v = uu[tid * OUT_LEN + l]; ns = fmaf(v, v, ns); }
        sc[tid] = sqrtf(ns) / (1.f + ns);
    }
    __syncthreads();

    // T1 = T0 + W^T @ (uu * sc)  -> stride-33 LDS (conflict-free writes)
    for (int e = tid; e < OUT_CAPS * IN_LEN; e += 256) {
        const int o = e >> 5, i = e & 31;
        float a = 0.f;
#pragma unroll
        for (int l = 0; l < OUT_LEN; ++l)
            a = fmaf(W[((size_t)o * OUT_LEN + l) * IN_LEN + i], uu[o * OUT_LEN + l], a);
        t_lds[o * TSTR + i] = T[(size_t)b * OUT_CAPS * IN_LEN + e] + a * sc[o];
    }
    __syncthreads();

    pass_v2(x, t_lds, buf, part2, b, c, tid, lane, wave);
}

// ---------------------------------------------------------------------------
// kC: final vt, split by o-group, XCD-aligned (R13-proven).
// ---------------------------------------------------------------------------
__global__ __launch_bounds__(256) void kC(const float* __restrict__ W,
                                          const float* __restrict__ part2,
                                          float* __restrict__ out) {
    const int d   = blockIdx.x;
    const int b   = (d & 7) * 4 + ((d >> 3) & 3);
    const int og  = d >> 5;              // 0..7
    const int tid = threadIdx.x;
    const int ol  = tid >> 5;            // 0..7 local o
    const int i   = tid & 31;            // input index / later l
    const int o   = og * 8 + ol;

    float a = 0.f;
    const float* pb = part2 + (size_t)b * NCHUNK * OUT_CAPS * IN_LEN + o * IN_LEN + i;
#pragma unroll
    for (int cc = 0; cc < NCHUNK; ++cc) a += pb[cc * OUT_CAPS * IN_LEN];

    __shared__ float s_lds[8][33];
    s_lds[ol][i] = a;
    __syncthreads();

    const float* wrow = W + ((size_t)o * OUT_LEN + i) * IN_LEN;
    float u = 0.f;
#pragma unroll
    for (int k = 0; k < IN_LEN; ++k) u = fmaf(wrow[k], s_lds[ol][k], u);

    float ns = u * u;
    ns += __shfl_xor(ns, 1, 64);
    ns += __shfl_xor(ns, 2, 64);
    ns += __shfl_xor(ns, 4, 64);
    ns += __shfl_xor(ns, 8, 64);
    ns += __shfl_xor(ns, 16, 64);
    const float scale = sqrtf(ns) / (1.f + ns);

    out[((size_t)b * OUT_CAPS + o) * OUT_LEN + i] = u * scale;
}

extern "C" void kernel_launch(void* const* d_in, const int* in_sizes, int n_in,
                              void* d_out, int out_size, void* d_ws, size_t ws_size,
                              hipStream_t stream) {
    const float* x = (const float*)d_in[0];   // [32,1152,32]
    const float* W = (const float*)d_in[1];   // [64,32,32]
    float* out = (float*)d_out;               // [32,64,32]

    float* T     = (float*)d_ws;                          // 256 KB
    float* part  = T + (size_t)N_B * OUT_CAPS * IN_LEN;   // 4 MB (iter-1 partials)
    float* part2 = part + (size_t)N_B * NCHUNK * OUT_CAPS * IN_LEN; // 4 MB (iter-2)

    kA<<<N_B * NCHUNK, 256, 0, stream>>>(x, W, T, part);          // init + iter 1
    kB<<<N_B * NCHUNK, 256, 0, stream>>>(x, W, T, part, part2);   // vt1 + iter 2
    kC<<<N_B * 8,      256, 0, stream>>>(W, part2, out);          // final vt
}

// Round 15
// 119.078 us; speedup vs baseline: 1.0889x; 1.0889x over previous
//
#include <hip/hip_runtime.h>
#include <math.h>

// CapsuleLinear dynamic routing, `priors` never materialized.
//   s[b,o,i]   = sum_n prob[b,o,n] * x[b,n,i]
//   out[b,o,l] = sum_i W[o,l,i] * s[b,o,i]
//   logits[b,o,n] = x[b,n,:] . T[b,o,:],  T accumulates t_r[o,i] = sum_l W[o,l,i]*v_r[o,l]
//
// R15: R13 base (120.6us best; R14's fused-init reverted — redundant init
// cost 27us of serial L2 work to save a 10us boundary). One change: the pass
// body processes 2 rows per iteration with interleaved softmax chains. The
// per-row serial chain (L2 load ~200cy -> 32-FMA logit -> 6-step DPP/shfl
// max -> exp -> 6-step sum -> 32-FMA accum ~ 650cy x 18 rows) is the
// dominant kernel-internal cost at 8 waves/CU; pairing rows halves the
// exposed latency. At (256,2) the VGPR cap is 256; 2-row state ~115 regs
// fits (R8's 4-row failed at (512,2) cap 128). Diagnostic: pass VGPR should
// rise 68 -> ~110-150; if it stays <=80 the compiler demoted again.
// Chain: k_init -> k_pass1 -> kB(vt1+pass2) -> kC(final vt). All else R13.

#define N_B      32
#define IN_CAPS  1152
#define IN_LEN   32
#define OUT_CAPS 64
#define OUT_LEN  32

#define NCHUNK 16                    // n-chunks per batch -> 512 pass blocks
#define NPB    (IN_CAPS / NCHUNK)    // 72 n per block
#define PASS_WAVES 4                 // 256-thread pass blocks
#define NPW    (NPB / PASS_WAVES)    // 18 n per wave
#define TSTR   33                    // t_lds row stride: bank (o+i)%32, conflict-free
#define FSTR   36                    // flush buf row stride (16B-aligned, R7-proven)

// XCD-aware decode of blockIdx.x -> (b,c): round-robin XCD = d&7 (R13-
// validated); each XCD gets 4 whole batches. Bijective (512%8==0).
#define DECODE_BC(d, b, c) \
    const int _slot = (d) >> 3; \
    const int b = ((d) & 7) * 4 + (_slot >> 4); \
    const int c = _slot & 15;

// DPP helper: butterfly step, all lanes valid.
#define DPPV(v, ctrl) \
    __int_as_float(__builtin_amdgcn_update_dpp(0, __float_as_int(v), ctrl, 0xF, 0xF, true))

__device__ __forceinline__ float wave_max(float v) {
    v = fmaxf(v, DPPV(v, 0xB1));         // quad_perm xor1
    v = fmaxf(v, DPPV(v, 0x4E));         // quad_perm xor2
    v = fmaxf(v, DPPV(v, 0x141));        // row_half_mirror
    v = fmaxf(v, DPPV(v, 0x140));        // row_mirror
    v = fmaxf(v, __shfl_xor(v, 16, 64)); // cross-row (proven path)
    v = fmaxf(v, __shfl_xor(v, 32, 64));
    return v;
}
__device__ __forceinline__ float wave_sum(float v) {
    v += DPPV(v, 0xB1);
    v += DPPV(v, 0x4E);
    v += DPPV(v, 0x141);
    v += DPPV(v, 0x140);
    v += __shfl_xor(v, 16, 64);
    v += __shfl_xor(v, 32, 64);
    return v;
}

// ---------------------------------------------------------------------------
// Pass body v3: 2 rows per iteration, interleaved softmax chains. t from
// conflict-free stride-33 LDS, x rows via broadcast VMEM, s[32] in regs.
// Flush: padded-LDS block reduce -> part[b,c] slab (R7-proven).
// ---------------------------------------------------------------------------
__device__ __forceinline__ void pass_v3(const float* __restrict__ x,
                                        const float* t_lds,   // [64*TSTR], filled
                                        float* buf,           // [4*64*FSTR]
                                        float* __restrict__ part_out,
                                        int b, int c, int tid, int lane, int wave) {
    float s[IN_LEN];
#pragma unroll
    for (int i = 0; i < IN_LEN; ++i) s[i] = 0.f;

    const float* xw = x + ((size_t)b * IN_CAPS + c * NPB + wave * NPW) * IN_LEN;
    const float* tr = t_lds + lane * TSTR;

#define LQ(acc, R, k) \
    acc = fmaf((R).x, tr[k],     acc); acc = fmaf((R).y, tr[k + 1], acc); \
    acc = fmaf((R).z, tr[k + 2], acc); acc = fmaf((R).w, tr[k + 3], acc);
#define SQ2(RA, RB, k) \
    s[k]     = fmaf(pr0, (RA).x, s[k]);     s[k]     = fmaf(pr1, (RB).x, s[k]); \
    s[k + 1] = fmaf(pr0, (RA).y, s[k + 1]); s[k + 1] = fmaf(pr1, (RB).y, s[k + 1]); \
    s[k + 2] = fmaf(pr0, (RA).z, s[k + 2]); s[k + 2] = fmaf(pr1, (RB).z, s[k + 2]); \
    s[k + 3] = fmaf(pr0, (RA).w, s[k + 3]); s[k + 3] = fmaf(pr1, (RB).w, s[k + 3]);

#pragma unroll
    for (int j = 0; j < NPW; j += 2) {
        const float4* xr0 = (const float4*)(xw + j * IN_LEN);        // uniform
        const float4* xr1 = (const float4*)(xw + (j + 1) * IN_LEN);  // uniform
        const float4 a0 = xr0[0], a1 = xr0[1], a2 = xr0[2], a3 = xr0[3],
                     a4 = xr0[4], a5 = xr0[5], a6 = xr0[6], a7 = xr0[7];
        const float4 b0 = xr1[0], b1 = xr1[1], b2 = xr1[2], b3 = xr1[3],
                     b4 = xr1[4], b5 = xr1[5], b6 = xr1[6], b7 = xr1[7];

        // two independent 4-chain logit reductions
        float u0 = 0.f, u1 = 0.f, u2 = 0.f, u3 = 0.f;
        float v0 = 0.f, v1 = 0.f, v2 = 0.f, v3 = 0.f;
        LQ(u0, a0, 0)  LQ(u1, a1, 4)  LQ(u2, a2, 8)  LQ(u3, a3, 12)
        LQ(v0, b0, 0)  LQ(v1, b1, 4)  LQ(v2, b2, 8)  LQ(v3, b3, 12)
        LQ(u0, a4, 16) LQ(u1, a5, 20) LQ(u2, a6, 24) LQ(u3, a7, 28)
        LQ(v0, b4, 16) LQ(v1, b5, 20) LQ(v2, b6, 24) LQ(v3, b7, 28)
        const float lg0 = (u0 + u1) + (u2 + u3);
        const float lg1 = (v0 + v1) + (v2 + v3);

        // interleaved softmax chains (independent -> scheduler overlaps)
        const float m0 = wave_max(lg0);
        const float m1 = wave_max(lg1);
        const float p0 = __expf(lg0 - m0);
        const float p1 = __expf(lg1 - m1);
        const float S0 = wave_sum(p0);
        const float S1 = wave_sum(p1);
        const float pr0 = p0 * __builtin_amdgcn_rcpf(S0);
        const float pr1 = p1 * __builtin_amdgcn_rcpf(S1);

        SQ2(a0, b0, 0)  SQ2(a1, b1, 4)  SQ2(a2, b2, 8)  SQ2(a3, b3, 12)
        SQ2(a4, b4, 16) SQ2(a5, b5, 20) SQ2(a6, b6, 24) SQ2(a7, b7, 28)
    }
#undef LQ
#undef SQ2

    // flush: per-wave rows into padded buf, block-reduce, write part[b,c]
    {
        float4* dst = (float4*)&buf[(wave * OUT_CAPS + lane) * FSTR];
#pragma unroll
        for (int q = 0; q < 8; ++q)
            dst[q] = make_float4(s[4 * q], s[4 * q + 1], s[4 * q + 2], s[4 * q + 3]);
    }
    __syncthreads();
    {
        float4* pb4 = (float4*)(part_out + ((size_t)b * NCHUNK + c) * OUT_CAPS * IN_LEN);
        for (int e = tid; e < OUT_CAPS * IN_LEN / 4; e += 256) {
            const int o = e >> 3, q4 = (e & 7) * 4;
            const float4 a0 = *(const float4*)&buf[(0 * OUT_CAPS + o) * FSTR + q4];
            const float4 a1 = *(const float4*)&buf[(1 * OUT_CAPS + o) * FSTR + q4];
            const float4 a2 = *(const float4*)&buf[(2 * OUT_CAPS + o) * FSTR + q4];
            const float4 a3 = *(const float4*)&buf[(3 * OUT_CAPS + o) * FSTR + q4];
            pb4[e] = make_float4(a0.x + a1.x + a2.x + a3.x,
                                 a0.y + a1.y + a2.y + a3.y,
                                 a0.z + a1.z + a2.z + a3.z,
                                 a0.w + a1.w + a2.w + a3.w);
        }
    }
}

// ---------------------------------------------------------------------------
// k_init: s0 = (1/64) sum_n x[b,n,:]; u = W@s0; squash; T = W^T@v0.
// 32 blocks x 512 threads, XCD-aligned batch (R13-proven).
// ---------------------------------------------------------------------------
__global__ __launch_bounds__(512) void k_init(const float* __restrict__ x,
                                              const float* __restrict__ W,
                                              float* __restrict__ T) {
    const int d   = blockIdx.x;
    const int b   = (d & 7) * 4 + (d >> 3);   // XCD-aligned batch
    const int tid = threadIdx.x;
    const float* xb = x + (size_t)b * IN_CAPS * IN_LEN;

    __shared__ float4 red4[64][8];            // 8 KB
    {
        const int q = tid & 7;
        const int g = tid >> 3;               // 0..63
        float4 acc = make_float4(0.f, 0.f, 0.f, 0.f);
        for (int n = g; n < IN_CAPS; n += 64) {   // 18 independent loads
            const float4 v = *(const float4*)(xb + n * IN_LEN + q * 4);
            acc.x += v.x; acc.y += v.y; acc.z += v.z; acc.w += v.w;
        }
        red4[g][q] = acc;
    }
    __syncthreads();
    __shared__ float s0[IN_LEN];
    if (tid < 8) {
        float4 v = make_float4(0.f, 0.f, 0.f, 0.f);
#pragma unroll 16
        for (int g = 0; g < 64; ++g) {
            const float4 r = red4[g][tid];
            v.x += r.x; v.y += r.y; v.z += r.z; v.w += r.w;
        }
        const float inv = 1.f / 64.f;   // uniform softmax prob at r=0
        s0[tid * 4 + 0] = v.x * inv;
        s0[tid * 4 + 1] = v.y * inv;
        s0[tid * 4 + 2] = v.z * inv;
        s0[tid * 4 + 3] = v.w * inv;
    }
    __syncthreads();

    __shared__ float u[OUT_CAPS * OUT_LEN];
    for (int e = tid; e < OUT_CAPS * OUT_LEN; e += 512) {
        const float* wrow = W + (size_t)e * IN_LEN;
        float a = 0.f;
#pragma unroll
        for (int i = 0; i < IN_LEN; ++i) a = fmaf(wrow[i], s0[i], a);
        u[e] = a;
    }
    __syncthreads();

    __shared__ float scale[OUT_CAPS];
    if (tid < OUT_CAPS) {
        float ns = 0.f;
#pragma unroll
        for (int l = 0; l < OUT_LEN; ++l) { const float v = u[tid * OUT_LEN + l]; ns = fmaf(v, v, ns); }
        scale[tid] = sqrtf(ns) / (1.f + ns);
    }
    __syncthreads();

    for (int e = tid; e < OUT_CAPS * IN_LEN; e += 512) {
        const int o = e >> 5, i = e & 31;
        float a = 0.f;
#pragma unroll
        for (int l = 0; l < OUT_LEN; ++l)
            a = fmaf(W[((size_t)o * OUT_LEN + l) * IN_LEN + i], u[o * OUT_LEN + l], a);
        T[(size_t)b * OUT_CAPS * IN_LEN + e] = a * scale[o];
    }
}

// ---------------------------------------------------------------------------
// k_pass1: stage T[b] -> stride-33 LDS, then routing iter 1 -> part.
// ---------------------------------------------------------------------------
__global__ __launch_bounds__(256, 2) void k_pass1(const float* __restrict__ x,
                                                  const float* __restrict__ T,
                                                  float* __restrict__ part) {
    DECODE_BC(blockIdx.x, b, c)
    const int tid  = threadIdx.x;
    const int lane = tid & 63;
    const int wave = __builtin_amdgcn_readfirstlane(tid >> 6);

    __shared__ float t_lds[OUT_CAPS * TSTR];                         // 8.25 KB
    __shared__ __align__(16) float buf[PASS_WAVES * OUT_CAPS * FSTR]; // 36 KB

    {
        const float* Tb = T + (size_t)b * OUT_CAPS * IN_LEN;
        for (int e = tid; e < OUT_CAPS * IN_LEN; e += 256)
            t_lds[(e >> 5) * TSTR + (e & 31)] = Tb[e];   // coalesced read, cf write
    }
    __syncthreads();

    pass_v3(x, t_lds, buf, part, b, c, tid, lane, wave);
}

// ---------------------------------------------------------------------------
// kB: redundant vt-reduce, wave-split (R13-proven); s -> u -> squash;
//     T1 = T0 + W^T v1 into stride-33 LDS; then routing iter 2 -> part2.
// ---------------------------------------------------------------------------
__global__ __launch_bounds__(256, 2) void kB(const float* __restrict__ x,
                                             const float* __restrict__ W,
                                             const float* __restrict__ T,
                                             const float* __restrict__ part,
                                             float* __restrict__ part2) {
    DECODE_BC(blockIdx.x, b, c)
    const int tid  = threadIdx.x;
    const int lane = tid & 63;
    const int wave = __builtin_amdgcn_readfirstlane(tid >> 6);

    __shared__ float t_lds[OUT_CAPS * TSTR];                          // 8.25 KB
    __shared__ __align__(16) float buf[PASS_WAVES * OUT_CAPS * FSTR]; // 36 KB

    float* uu = buf + 2048;   // 2048 floats
    float* sc = buf + 4096;   // 64

    // ---- vt-reduce, wave-split: 4x memory parallelism, chain depth 8x4 ----
    {
        const float4* pb4 = (const float4*)(part + (size_t)b * NCHUNK * OUT_CAPS * IN_LEN);
        float4* wp = (float4*)buf + wave * 512;
        for (int e = lane; e < 512; e += 64) {
            float4 acc = make_float4(0.f, 0.f, 0.f, 0.f);
#pragma unroll
            for (int k = 0; k < 4; ++k) {
                const float4 v = pb4[(size_t)(wave + 4 * k) * 512 + e];
                acc.x += v.x; acc.y += v.y; acc.z += v.z; acc.w += v.w;
            }
            wp[e] = acc;
        }
    }
    __syncthreads();
    {
        float4* b4 = (float4*)buf;
        for (int e = tid; e < 512; e += 256) {
            const float4 a0 = b4[e], a1 = b4[512 + e], a2 = b4[1024 + e], a3 = b4[1536 + e];
            b4[e] = make_float4(a0.x + a1.x + a2.x + a3.x,
                                a0.y + a1.y + a2.y + a3.y,
                                a0.z + a1.z + a2.z + a3.z,
                                a0.w + a1.w + a2.w + a3.w);   // s -> buf[0..2048)
        }
    }
    __syncthreads();

    for (int e = tid; e < OUT_CAPS * OUT_LEN; e += 256) {
        const int o = e >> 5;
        const float* wrow = W + (size_t)e * IN_LEN;
        const float* srow = buf + o * IN_LEN;
        float a = 0.f;
#pragma unroll
        for (int i = 0; i < IN_LEN; ++i) a = fmaf(wrow[i], srow[i], a);
        uu[e] = a;
    }
    __syncthreads();
    if (tid < OUT_CAPS) {
        float ns = 0.f;
#pragma unroll
        for (int l = 0; l < OUT_LEN; ++l) { const float v = uu[tid * OUT_LEN + l]; ns = fmaf(v, v, ns); }
        sc[tid] = sqrtf(ns) / (1.f + ns);
    }
    __syncthreads();

    // T1 = T0 + W^T @ (uu * sc)  -> stride-33 LDS (conflict-free writes)
    for (int e = tid; e < OUT_CAPS * IN_LEN; e += 256) {
        const int o = e >> 5, i = e & 31;
        float a = 0.f;
#pragma unroll
        for (int l = 0; l < OUT_LEN; ++l)
            a = fmaf(W[((size_t)o * OUT_LEN + l) * IN_LEN + i], uu[o * OUT_LEN + l], a);
        t_lds[o * TSTR + i] = T[(size_t)b * OUT_CAPS * IN_LEN + e] + a * sc[o];
    }
    __syncthreads();

    pass_v3(x, t_lds, buf, part2, b, c, tid, lane, wave);
}

// ---------------------------------------------------------------------------
// kC: final vt, split by o-group, XCD-aligned (R13-proven).
// ---------------------------------------------------------------------------
__global__ __launch_bounds__(256) void kC(const float* __restrict__ W,
                                          const float* __restrict__ part2,
                                          float* __restrict__ out) {
    const int d   = blockIdx.x;
    const int b   = (d & 7) * 4 + ((d >> 3) & 3);
    const int og  = d >> 5;              // 0..7
    const int tid = threadIdx.x;
    const int ol  = tid >> 5;            // 0..7 local o
    const int i   = tid & 31;            // input index / later l
    const int o   = og * 8 + ol;

    float a = 0.f;
    const float* pb = part2 + (size_t)b * NCHUNK * OUT_CAPS * IN_LEN + o * IN_LEN + i;
#pragma unroll
    for (int cc = 0; cc < NCHUNK; ++cc) a += pb[cc * OUT_CAPS * IN_LEN];

    __shared__ float s_lds[8][33];
    s_lds[ol][i] = a;
    __syncthreads();

    const float* wrow = W + ((size_t)o * OUT_LEN + i) * IN_LEN;
    float u = 0.f;
#pragma unroll
    for (int k = 0; k < IN_LEN; ++k) u = fmaf(wrow[k], s_lds[ol][k], u);

    float ns = u * u;
    ns += __shfl_xor(ns, 1, 64);
    ns += __shfl_xor(ns, 2, 64);
    ns += __shfl_xor(ns, 4, 64);
    ns += __shfl_xor(ns, 8, 64);
    ns += __shfl_xor(ns, 16, 64);
    const float scale = sqrtf(ns) / (1.f + ns);

    out[((size_t)b * OUT_CAPS + o) * OUT_LEN + i] = u * scale;
}

extern "C" void kernel_launch(void* const* d_in, const int* in_sizes, int n_in,
                              void* d_out, int out_size, void* d_ws, size_t ws_size,
                              hipStream_t stream) {
    const float* x = (const float*)d_in[0];   // [32,1152,32]
    const float* W = (const float*)d_in[1];   // [64,32,32]
    float* out = (float*)d_out;               // [32,64,32]

    float* T     = (float*)d_ws;                          // 256 KB
    float* part  = T + (size_t)N_B * OUT_CAPS * IN_LEN;   // 4 MB (iter-1 partials)
    float* part2 = part + (size_t)N_B * NCHUNK * OUT_CAPS * IN_LEN; // 4 MB (iter-2)

    k_init <<<N_B,          512, 0, stream>>>(x, W, T);
    k_pass1<<<N_B * NCHUNK, 256, 0, stream>>>(x, T, part);           // iter 1
    kB     <<<N_B * NCHUNK, 256, 0, stream>>>(x, W, T, part, part2); // vt1 + iter 2
    kC     <<<N_B * 8,      256, 0, stream>>>(W, part2, out);        // final vt
}

// Round 16
// 118.755 us; speedup vs baseline: 1.0919x; 1.0027x over previous
//
#include <hip/hip_runtime.h>
#include <math.h>

// CapsuleLinear dynamic routing, `priors` never materialized.
//   s[b,o,i]   = sum_n prob[b,o,n] * x[b,n,i]
//   out[b,o,l] = sum_i W[o,l,i] * s[b,o,i]
//   logits[b,o,n] = x[b,n,:] . T[b,o,:],  T accumulates t_r[o,i] = sum_l W[o,l,i]*v_r[o,l]
//
// R16: R15 base (119.1us best) + final ILP squeeze: pass body processes
// 3 rows/iteration (18 = 3x6) with interleaved softmax chains (~150 live
// VGPR, fits (256,2) cap 256), and kB's vt-reduce e-loop unrolled 2x
// (doubles loads in flight). All else R15/R13-verbatim: 512-thread XCD-
// aligned k_init, stride-33 t_lds, wave-split vt-reduce, XCD-aligned kC.
// Chain: k_init -> k_pass1 -> kB(vt1+pass2) -> kC(final vt).
// Pre-committed stop rule: if >= ~118us, declare orchestration floor.

#define N_B      32
#define IN_CAPS  1152
#define IN_LEN   32
#define OUT_CAPS 64
#define OUT_LEN  32

#define NCHUNK 16                    // n-chunks per batch -> 512 pass blocks
#define NPB    (IN_CAPS / NCHUNK)    // 72 n per block
#define PASS_WAVES 4                 // 256-thread pass blocks
#define NPW    (NPB / PASS_WAVES)    // 18 n per wave
#define TSTR   33                    // t_lds row stride: bank (o+i)%32, conflict-free
#define FSTR   36                    // flush buf row stride (16B-aligned, R7-proven)

// XCD-aware decode of blockIdx.x -> (b,c): round-robin XCD = d&7 (R13-
// validated); each XCD gets 4 whole batches. Bijective (512%8==0).
#define DECODE_BC(d, b, c) \
    const int _slot = (d) >> 3; \
    const int b = ((d) & 7) * 4 + (_slot >> 4); \
    const int c = _slot & 15;

// DPP helper: butterfly step, all lanes valid.
#define DPPV(v, ctrl) \
    __int_as_float(__builtin_amdgcn_update_dpp(0, __float_as_int(v), ctrl, 0xF, 0xF, true))

__device__ __forceinline__ float wave_max(float v) {
    v = fmaxf(v, DPPV(v, 0xB1));         // quad_perm xor1
    v = fmaxf(v, DPPV(v, 0x4E));         // quad_perm xor2
    v = fmaxf(v, DPPV(v, 0x141));        // row_half_mirror
    v = fmaxf(v, DPPV(v, 0x140));        // row_mirror
    v = fmaxf(v, __shfl_xor(v, 16, 64)); // cross-row (proven path)
    v = fmaxf(v, __shfl_xor(v, 32, 64));
    return v;
}
__device__ __forceinline__ float wave_sum(float v) {
    v += DPPV(v, 0xB1);
    v += DPPV(v, 0x4E);
    v += DPPV(v, 0x141);
    v += DPPV(v, 0x140);
    v += __shfl_xor(v, 16, 64);
    v += __shfl_xor(v, 32, 64);
    return v;
}

// ---------------------------------------------------------------------------
// Pass body v4: 3 rows per iteration, interleaved softmax chains. t from
// conflict-free stride-33 LDS, x rows via broadcast VMEM, s[32] in regs.
// Flush: padded-LDS block reduce -> part[b,c] slab (R7-proven).
// ---------------------------------------------------------------------------
__device__ __forceinline__ void pass_v4(const float* __restrict__ x,
                                        const float* t_lds,   // [64*TSTR], filled
                                        float* buf,           // [4*64*FSTR]
                                        float* __restrict__ part_out,
                                        int b, int c, int tid, int lane, int wave) {
    float s[IN_LEN];
#pragma unroll
    for (int i = 0; i < IN_LEN; ++i) s[i] = 0.f;

    const float* xw = x + ((size_t)b * IN_CAPS + c * NPB + wave * NPW) * IN_LEN;
    const float* tr = t_lds + lane * TSTR;

#define LQ(acc, R, k) \
    acc = fmaf((R).x, tr[k],     acc); acc = fmaf((R).y, tr[k + 1], acc); \
    acc = fmaf((R).z, tr[k + 2], acc); acc = fmaf((R).w, tr[k + 3], acc);
#define SQ3(RA, RB, RC, k) \
    s[k]     = fmaf(pr0, (RA).x, s[k]);     s[k]     = fmaf(pr1, (RB).x, s[k]); \
    s[k]     = fmaf(pr2, (RC).x, s[k]); \
    s[k + 1] = fmaf(pr0, (RA).y, s[k + 1]); s[k + 1] = fmaf(pr1, (RB).y, s[k + 1]); \
    s[k + 1] = fmaf(pr2, (RC).y, s[k + 1]); \
    s[k + 2] = fmaf(pr0, (RA).z, s[k + 2]); s[k + 2] = fmaf(pr1, (RB).z, s[k + 2]); \
    s[k + 2] = fmaf(pr2, (RC).z, s[k + 2]); \
    s[k + 3] = fmaf(pr0, (RA).w, s[k + 3]); s[k + 3] = fmaf(pr1, (RB).w, s[k + 3]); \
    s[k + 3] = fmaf(pr2, (RC).w, s[k + 3]);

#pragma unroll
    for (int j = 0; j < NPW; j += 3) {
        const float4* xr0 = (const float4*)(xw + j * IN_LEN);        // uniform
        const float4* xr1 = (const float4*)(xw + (j + 1) * IN_LEN);  // uniform
        const float4* xr2 = (const float4*)(xw + (j + 2) * IN_LEN);  // uniform
        const float4 a0 = xr0[0], a1 = xr0[1], a2 = xr0[2], a3 = xr0[3],
                     a4 = xr0[4], a5 = xr0[5], a6 = xr0[6], a7 = xr0[7];
        const float4 b0 = xr1[0], b1 = xr1[1], b2 = xr1[2], b3 = xr1[3],
                     b4 = xr1[4], b5 = xr1[5], b6 = xr1[6], b7 = xr1[7];
        const float4 c0 = xr2[0], c1 = xr2[1], c2 = xr2[2], c3 = xr2[3],
                     c4 = xr2[4], c5 = xr2[5], c6 = xr2[6], c7 = xr2[7];

        // three independent 4-chain logit reductions
        float u0 = 0.f, u1 = 0.f, u2 = 0.f, u3 = 0.f;
        float v0 = 0.f, v1 = 0.f, v2 = 0.f, v3 = 0.f;
        float w0 = 0.f, w1 = 0.f, w2 = 0.f, w3 = 0.f;
        LQ(u0, a0, 0)  LQ(u1, a1, 4)  LQ(u2, a2, 8)  LQ(u3, a3, 12)
        LQ(v0, b0, 0)  LQ(v1, b1, 4)  LQ(v2, b2, 8)  LQ(v3, b3, 12)
        LQ(w0, c0, 0)  LQ(w1, c1, 4)  LQ(w2, c2, 8)  LQ(w3, c3, 12)
        LQ(u0, a4, 16) LQ(u1, a5, 20) LQ(u2, a6, 24) LQ(u3, a7, 28)
        LQ(v0, b4, 16) LQ(v1, b5, 20) LQ(v2, b6, 24) LQ(v3, b7, 28)
        LQ(w0, c4, 16) LQ(w1, c5, 20) LQ(w2, c6, 24) LQ(w3, c7, 28)
        const float lg0 = (u0 + u1) + (u2 + u3);
        const float lg1 = (v0 + v1) + (v2 + v3);
        const float lg2 = (w0 + w1) + (w2 + w3);

        // interleaved softmax chains (independent -> scheduler overlaps)
        const float m0 = wave_max(lg0);
        const float m1 = wave_max(lg1);
        const float m2 = wave_max(lg2);
        const float p0 = __expf(lg0 - m0);
        const float p1 = __expf(lg1 - m1);
        const float p2 = __expf(lg2 - m2);
        const float S0 = wave_sum(p0);
        const float S1 = wave_sum(p1);
        const float S2 = wave_sum(p2);
        const float pr0 = p0 * __builtin_amdgcn_rcpf(S0);
        const float pr1 = p1 * __builtin_amdgcn_rcpf(S1);
        const float pr2 = p2 * __builtin_amdgcn_rcpf(S2);

        SQ3(a0, b0, c0, 0)  SQ3(a1, b1, c1, 4)  SQ3(a2, b2, c2, 8)  SQ3(a3, b3, c3, 12)
        SQ3(a4, b4, c4, 16) SQ3(a5, b5, c5, 20) SQ3(a6, b6, c6, 24) SQ3(a7, b7, c7, 28)
    }
#undef LQ
#undef SQ3

    // flush: per-wave rows into padded buf, block-reduce, write part[b,c]
    {
        float4* dst = (float4*)&buf[(wave * OUT_CAPS + lane) * FSTR];
#pragma unroll
        for (int q = 0; q < 8; ++q)
            dst[q] = make_float4(s[4 * q], s[4 * q + 1], s[4 * q + 2], s[4 * q + 3]);
    }
    __syncthreads();
    {
        float4* pb4 = (float4*)(part_out + ((size_t)b * NCHUNK + c) * OUT_CAPS * IN_LEN);
        for (int e = tid; e < OUT_CAPS * IN_LEN / 4; e += 256) {
            const int o = e >> 3, q4 = (e & 7) * 4;
            const float4 a0 = *(const float4*)&buf[(0 * OUT_CAPS + o) * FSTR + q4];
            const float4 a1 = *(const float4*)&buf[(1 * OUT_CAPS + o) * FSTR + q4];
            const float4 a2 = *(const float4*)&buf[(2 * OUT_CAPS + o) * FSTR + q4];
            const float4 a3 = *(const float4*)&buf[(3 * OUT_CAPS + o) * FSTR + q4];
            pb4[e] = make_float4(a0.x + a1.x + a2.x + a3.x,
                                 a0.y + a1.y + a2.y + a3.y,
                                 a0.z + a1.z + a2.z + a3.z,
                                 a0.w + a1.w + a2.w + a3.w);
        }
    }
}

// ---------------------------------------------------------------------------
// k_init: s0 = (1/64) sum_n x[b,n,:]; u = W@s0; squash; T = W^T@v0.
// 32 blocks x 512 threads, XCD-aligned batch (R13-proven).
// ---------------------------------------------------------------------------
__global__ __launch_bounds__(512) void k_init(const float* __restrict__ x,
                                              const float* __restrict__ W,
                                              float* __restrict__ T) {
    const int d   = blockIdx.x;
    const int b   = (d & 7) * 4 + (d >> 3);   // XCD-aligned batch
    const int tid = threadIdx.x;
    const float* xb = x + (size_t)b * IN_CAPS * IN_LEN;

    __shared__ float4 red4[64][8];            // 8 KB
    {
        const int q = tid & 7;
        const int g = tid >> 3;               // 0..63
        float4 acc = make_float4(0.f, 0.f, 0.f, 0.f);
        for (int n = g; n < IN_CAPS; n += 64) {   // 18 independent loads
            const float4 v = *(const float4*)(xb + n * IN_LEN + q * 4);
            acc.x += v.x; acc.y += v.y; acc.z += v.z; acc.w += v.w;
        }
        red4[g][q] = acc;
    }
    __syncthreads();
    __shared__ float s0[IN_LEN];
    if (tid < 8) {
        float4 v = make_float4(0.f, 0.f, 0.f, 0.f);
#pragma unroll 16
        for (int g = 0; g < 64; ++g) {
            const float4 r = red4[g][tid];
            v.x += r.x; v.y += r.y; v.z += r.z; v.w += r.w;
        }
        const float inv = 1.f / 64.f;   // uniform softmax prob at r=0
        s0[tid * 4 + 0] = v.x * inv;
        s0[tid * 4 + 1] = v.y * inv;
        s0[tid * 4 + 2] = v.z * inv;
        s0[tid * 4 + 3] = v.w * inv;
    }
    __syncthreads();

    __shared__ float u[OUT_CAPS * OUT_LEN];
    for (int e = tid; e < OUT_CAPS * OUT_LEN; e += 512) {
        const float* wrow = W + (size_t)e * IN_LEN;
        float a = 0.f;
#pragma unroll
        for (int i = 0; i < IN_LEN; ++i) a = fmaf(wrow[i], s0[i], a);
        u[e] = a;
    }
    __syncthreads();

    __shared__ float scale[OUT_CAPS];
    if (tid < OUT_CAPS) {
        float ns = 0.f;
#pragma unroll
        for (int l = 0; l < OUT_LEN; ++l) { const float v = u[tid * OUT_LEN + l]; ns = fmaf(v, v, ns); }
        scale[tid] = sqrtf(ns) / (1.f + ns);
    }
    __syncthreads();

    for (int e = tid; e < OUT_CAPS * IN_LEN; e += 512) {
        const int o = e >> 5, i = e & 31;
        float a = 0.f;
#pragma unroll
        for (int l = 0; l < OUT_LEN; ++l)
            a = fmaf(W[((size_t)o * OUT_LEN + l) * IN_LEN + i], u[o * OUT_LEN + l], a);
        T[(size_t)b * OUT_CAPS * IN_LEN + e] = a * scale[o];
    }
}

// ---------------------------------------------------------------------------
// k_pass1: stage T[b] -> stride-33 LDS, then routing iter 1 -> part.
// ---------------------------------------------------------------------------
__global__ __launch_bounds__(256, 2) void k_pass1(const float* __restrict__ x,
                                                  const float* __restrict__ T,
                                                  float* __restrict__ part) {
    DECODE_BC(blockIdx.x, b, c)
    const int tid  = threadIdx.x;
    const int lane = tid & 63;
    const int wave = __builtin_amdgcn_readfirstlane(tid >> 6);

    __shared__ float t_lds[OUT_CAPS * TSTR];                         // 8.25 KB
    __shared__ __align__(16) float buf[PASS_WAVES * OUT_CAPS * FSTR]; // 36 KB

    {
        const float* Tb = T + (size_t)b * OUT_CAPS * IN_LEN;
        for (int e = tid; e < OUT_CAPS * IN_LEN; e += 256)
            t_lds[(e >> 5) * TSTR + (e & 31)] = Tb[e];   // coalesced read, cf write
    }
    __syncthreads();

    pass_v4(x, t_lds, buf, part, b, c, tid, lane, wave);
}

// ---------------------------------------------------------------------------
// kB: redundant vt-reduce, wave-split + unroll-2 (8 loads in flight);
//     s -> u -> squash; T1 = T0 + W^T v1 into stride-33 LDS; then routing
//     iter 2 -> part2.
// ---------------------------------------------------------------------------
__global__ __launch_bounds__(256, 2) void kB(const float* __restrict__ x,
                                             const float* __restrict__ W,
                                             const float* __restrict__ T,
                                             const float* __restrict__ part,
                                             float* __restrict__ part2) {
    DECODE_BC(blockIdx.x, b, c)
    const int tid  = threadIdx.x;
    const int lane = tid & 63;
    const int wave = __builtin_amdgcn_readfirstlane(tid >> 6);

    __shared__ float t_lds[OUT_CAPS * TSTR];                          // 8.25 KB
    __shared__ __align__(16) float buf[PASS_WAVES * OUT_CAPS * FSTR]; // 36 KB

    float* uu = buf + 2048;   // 2048 floats
    float* sc = buf + 4096;   // 64

    // ---- vt-reduce, wave-split: 4x memory parallelism, chain depth 8x4 ----
    {
        const float4* pb4 = (const float4*)(part + (size_t)b * NCHUNK * OUT_CAPS * IN_LEN);
        float4* wp = (float4*)buf + wave * 512;
#pragma unroll 2
        for (int e = lane; e < 512; e += 64) {
            float4 acc = make_float4(0.f, 0.f, 0.f, 0.f);
#pragma unroll
            for (int k = 0; k < 4; ++k) {
                const float4 v = pb4[(size_t)(wave + 4 * k) * 512 + e];
                acc.x += v.x; acc.y += v.y; acc.z += v.z; acc.w += v.w;
            }
            wp[e] = acc;
        }
    }
    __syncthreads();
    {
        float4* b4 = (float4*)buf;
        for (int e = tid; e < 512; e += 256) {
            const float4 a0 = b4[e], a1 = b4[512 + e], a2 = b4[1024 + e], a3 = b4[1536 + e];
            b4[e] = make_float4(a0.x + a1.x + a2.x + a3.x,
                                a0.y + a1.y + a2.y + a3.y,
                                a0.z + a1.z + a2.z + a3.z,
                                a0.w + a1.w + a2.w + a3.w);   // s -> buf[0..2048)
        }
    }
    __syncthreads();

    for (int e = tid; e < OUT_CAPS * OUT_LEN; e += 256) {
        const int o = e >> 5;
        const float* wrow = W + (size_t)e * IN_LEN;
        const float* srow = buf + o * IN_LEN;
        float a = 0.f;
#pragma unroll
        for (int i = 0; i < IN_LEN; ++i) a = fmaf(wrow[i], srow[i], a);
        uu[e] = a;
    }
    __syncthreads();
    if (tid < OUT_CAPS) {
        float ns = 0.f;
#pragma unroll
        for (int l = 0; l < OUT_LEN; ++l) { const float v = uu[tid * OUT_LEN + l]; ns = fmaf(v, v, ns); }
        sc[tid] = sqrtf(ns) / (1.f + ns);
    }
    __syncthreads();

    // T1 = T0 + W^T @ (uu * sc)  -> stride-33 LDS (conflict-free writes)
    for (int e = tid; e < OUT_CAPS * IN_LEN; e += 256) {
        const int o = e >> 5, i = e & 31;
        float a = 0.f;
#pragma unroll
        for (int l = 0; l < OUT_LEN; ++l)
            a = fmaf(W[((size_t)o * OUT_LEN + l) * IN_LEN + i], uu[o * OUT_LEN + l], a);
        t_lds[o * TSTR + i] = T[(size_t)b * OUT_CAPS * IN_LEN + e] + a * sc[o];
    }
    __syncthreads();

    pass_v4(x, t_lds, buf, part2, b, c, tid, lane, wave);
}

// ---------------------------------------------------------------------------
// kC: final vt, split by o-group, XCD-aligned (R13-proven).
// ---------------------------------------------------------------------------
__global__ __launch_bounds__(256) void kC(const float* __restrict__ W,
                                          const float* __restrict__ part2,
                                          float* __restrict__ out) {
    const int d   = blockIdx.x;
    const int b   = (d & 7) * 4 + ((d >> 3) & 3);
    const int og  = d >> 5;              // 0..7
    const int tid = threadIdx.x;
    const int ol  = tid >> 5;            // 0..7 local o
    const int i   = tid & 31;            // input index / later l
    const int o   = og * 8 + ol;

    float a = 0.f;
    const float* pb = part2 + (size_t)b * NCHUNK * OUT_CAPS * IN_LEN + o * IN_LEN + i;
#pragma unroll
    for (int cc = 0; cc < NCHUNK; ++cc) a += pb[cc * OUT_CAPS * IN_LEN];

    __shared__ float s_lds[8][33];
    s_lds[ol][i] = a;
    __syncthreads();

    const float* wrow = W + ((size_t)o * OUT_LEN + i) * IN_LEN;
    float u = 0.f;
#pragma unroll
    for (int k = 0; k < IN_LEN; ++k) u = fmaf(wrow[k], s_lds[ol][k], u);

    float ns = u * u;
    ns += __shfl_xor(ns, 1, 64);
    ns += __shfl_xor(ns, 2, 64);
    ns += __shfl_xor(ns, 4, 64);
    ns += __shfl_xor(ns, 8, 64);
    ns += __shfl_xor(ns, 16, 64);
    const float scale = sqrtf(ns) / (1.f + ns);

    out[((size_t)b * OUT_CAPS + o) * OUT_LEN + i] = u * scale;
}

extern "C" void kernel_launch(void* const* d_in, const int* in_sizes, int n_in,
                              void* d_out, int out_size, void* d_ws, size_t ws_size,
                              hipStream_t stream) {
    const float* x = (const float*)d_in[0];   // [32,1152,32]
    const float* W = (const float*)d_in[1];   // [64,32,32]
    float* out = (float*)d_out;               // [32,64,32]

    float* T     = (float*)d_ws;                          // 256 KB
    float* part  = T + (size_t)N_B * OUT_CAPS * IN_LEN;   // 4 MB (iter-1 partials)
    float* part2 = part + (size_t)N_B * NCHUNK * OUT_CAPS * IN_LEN; // 4 MB (iter-2)

    k_init <<<N_B,          512, 0, stream>>>(x, W, T);
    k_pass1<<<N_B * NCHUNK, 256, 0, stream>>>(x, T, part);           // iter 1
    kB     <<<N_B * NCHUNK, 256, 0, stream>>>(x, W, T, part, part2); // vt1 + iter 2
    kC     <<<N_B * 8,      256, 0, stream>>>(W, part2, out);        // final vt
}